// Round 19
// baseline (30.185 us; speedup 1.0000x reference)
//
#include <hip/hip_runtime.h>
#include <math.h>

// DeepFeatureLoss: B=2, N=4096, D=32, fp32 in/out.
// out[0..1] = ce_loss[b], out[2..3] = reg_loss[b].
//
// ce_i = log(s_f) - t/s_p  (softmax max pinned at 0; dists <= 0):
//   s_p = sum_j exp(pd_ij), t = sum_j exp(pd_ij)*fd_ij, s_f = sum_j exp(fd_ij)
// exp2 units; t *= LN2 at finalize.
//
// R19 = R18 (best, 25.0us) + ONE change: ep-side skip. pd' < -45 =>
// exp2(pd')==0 in fp32 exactly; ~84% of 16x16 tiles have all pd' < -45
// (unsorted uniform points, sigma=0.005). Test is register-only
// (fmax3 over the pd f4 already produced by the point MFMA + __any,
// wave-uniform branch) gating ONLY {4 ep exps, sp+=, tA fma}. No masks,
// no extra kernels, no divergence — unlike R9/R14/R15/R16/R17 deliveries.
// Dropped terms <= 2^-45*|fd|: invisible in fp32 sums.
//
// ws (floats): nrm1[0,16384) nrm2[16384,32768) fragB[32768,294912)
// fragA[294912,557056) regp[557056,565248) part[565248,614400).

#define NPTS 4096
#define ROWS_TOT 8192
#define DF 32

#define L2E  1.4426950408889634f
#define LN2  0.6931471805599453f
#define FSC  1.6986436f           // sqrt(2*log2e)
#define PSC2 339.72872f           // 200*sqrt(2*log2e)
#define PDCUT (-45.0f)            // exp2(x) == 0 in fp32 for x < -149; -45 is
                                  // where contributions drop below fp32 lsb

typedef _Float16 half8 __attribute__((ext_vector_type(8)));
typedef float f4 __attribute__((ext_vector_type(4)));

// ---- kA: combined fragments (feature + hi/lo point) + norm float2s ----
__global__ void kA_prep(const float* __restrict__ pts,
                        const float* __restrict__ f1g,
                        const float* __restrict__ f2g,
                        float2* __restrict__ nrm1, float2* __restrict__ nrm2,
                        _Float16* __restrict__ fragA, _Float16* __restrict__ fragB,
                        float* __restrict__ regp, float* __restrict__ out) {
    const int r = blockIdx.x * 64 + threadIdx.x;     // 0..8191
    if (r < 4) out[r] = 0.0f;
    const int jt = r >> 4;                           // global tile id 0..511
    const int c  = r & 15;                           // row/col within tile

    float n1, n2, reg1, reg2;
    {   // features -> [0,64) of tile block
        const float4* f2v = (const float4*)(f2g + (size_t)r * DF);
        float vals[32]; float s = 0.0f;
#pragma unroll
        for (int q = 0; q < 8; ++q) {
            float4 v = f2v[q];
            vals[4*q]=v.x; vals[4*q+1]=v.y; vals[4*q+2]=v.z; vals[4*q+3]=v.w;
            s += v.x*v.x + v.y*v.y + v.z*v.z + v.w*v.w;
        }
        n2 = s;
        reg2 = s - vals[0]*vals[0] - vals[1]*vals[1] - vals[2]*vals[2];
        half8* fv = (half8*)fragB;
#pragma unroll
        for (int kb = 0; kb < 4; ++kb) {
            half8 h;
#pragma unroll
            for (int i = 0; i < 8; ++i) h[i] = (_Float16)(vals[kb*8+i] * FSC);
            fv[(size_t)jt*128 + kb*16 + c] = h;
        }
    }
    {
        const float4* f1v = (const float4*)(f1g + (size_t)r * DF);
        float vals[32]; float s = 0.0f;
#pragma unroll
        for (int q = 0; q < 8; ++q) {
            float4 v = f1v[q];
            vals[4*q]=v.x; vals[4*q+1]=v.y; vals[4*q+2]=v.z; vals[4*q+3]=v.w;
            s += v.x*v.x + v.y*v.y + v.z*v.z + v.w*v.w;
        }
        n1 = s;
        reg1 = s - vals[0]*vals[0] - vals[1]*vals[1] - vals[2]*vals[2];
        half8* fv = (half8*)fragA;
#pragma unroll
        for (int kb = 0; kb < 4; ++kb) {
            half8 h;
#pragma unroll
            for (int i = 0; i < 8; ++i) h[i] = (_Float16)(vals[kb*8+i] * FSC);
            fv[(size_t)jt*128 + kb*16 + c] = h;
        }
    }
    {   // points hi/lo -> [64,128) of tile block
        const float* pp = pts + (size_t)r * 3;
        const float v0 = pp[0]*PSC2, v1 = pp[1]*PSC2, v2 = pp[2]*PSC2;
        const float h0 = (float)(_Float16)v0, h1 = (float)(_Float16)v1,
                    h2 = (float)(_Float16)v2;
        const float l0 = v0 - h0, l1 = v1 - h1, l2 = v2 - h2;
        const float np = 0.5f * (v0*v0 + v1*v1 + v2*v2);

        const float pa[16] = {h0,h1,h2,h0,h1,h2,l0,l1,  l2,l0,l1,l2,0,0,0,0};
        const float pb[16] = {h0,h1,h2,l0,l1,l2,h0,h1,  h2,l0,l1,l2,0,0,0,0};
        half8* fa = (half8*)fragA;
        half8* fb = (half8*)fragB;
#pragma unroll
        for (int kb = 0; kb < 2; ++kb) {
            half8 ha, hb;
#pragma unroll
            for (int i = 0; i < 8; ++i) {
                ha[i] = (_Float16)pa[kb*8+i];
                hb[i] = (_Float16)pb[kb*8+i];
            }
            fa[(size_t)jt*128 + 64 + kb*16 + c] = ha;
            fb[(size_t)jt*128 + 64 + kb*16 + c] = hb;
        }
        const half8 z = {0,0,0,0,0,0,0,0};
        fa[(size_t)jt*128 + 64 + 32 + c] = z;  fa[(size_t)jt*128 + 64 + 48 + c] = z;
        fb[(size_t)jt*128 + 64 + 32 + c] = z;  fb[(size_t)jt*128 + 64 + 48 + c] = z;

        nrm1[r] = make_float2(-(n1 * L2E), -np);     // row side (negated)
        nrm2[r] = make_float2(  n2 * L2E,   np);     // col side (positive)
    }
    regp[r] = reg1 + reg2;
}

// ---- kB: MI=2; 4 MFMA/iter; ep-side gated by register-only __any test ----
__launch_bounds__(512)
__global__ void kB_main(const float2* __restrict__ nrm1,
                        const float2* __restrict__ nrm2,
                        const _Float16* __restrict__ fragA,
                        const _Float16* __restrict__ fragB,
                        float* __restrict__ part) {
    __shared__ float sS[8][32], sT[8][32], sF[8][32];

    const int tid = threadIdx.x;
    const int l = tid & 63, wv = tid >> 6;           // wave 0..7
    const int ip = blockIdx.x >> 1;                  // i-pair 0..255
    const int jh = blockIdx.x & 1;                   // j-half 0/1
    const int b  = ip >> 7;
    const int i0g = ip * 32;
    const int lr = l & 15, lk = l >> 4;

    const half8 afFA = ((const half8*)fragA)[(size_t)(ip*2)   * 128 + l];
    const half8 afPA = ((const half8*)fragA)[(size_t)(ip*2)   * 128 + 64 + l];
    const half8 afFB = ((const half8*)fragA)[(size_t)(ip*2+1) * 128 + l];
    const half8 afPB = ((const half8*)fragA)[(size_t)(ip*2+1) * 128 + 64 + l];

    const int rbA = i0g + lk * 4;
    const int rbB = i0g + 16 + lk * 4;
    f4 qfA, qpA, qfB, qpB;                           // -nf1', -np1' per row
#pragma unroll
    for (int e = 0; e < 4; ++e) {
        const float2 a = nrm1[rbA + e];
        const float2 bq = nrm1[rbB + e];
        qfA[e] = a.x;  qpA[e] = a.y;
        qfB[e] = bq.x; qpB[e] = bq.y;
    }

    const int jt0 = b * 256 + jh * 128 + wv * 16;
    const int j0  = b * NPTS + jh * 2048 + wv * 256 + lr;
    const half8*  fbase = (const half8*)fragB + ((size_t)jt0 * 128 + l);
    const float2* nbase = nrm2 + j0;

    f4 spA = {0,0,0,0}, tAA = {0,0,0,0}, sfA = {0,0,0,0};
    f4 spB = {0,0,0,0}, tAB = {0,0,0,0}, sfB = {0,0,0,0};

    half8  bfFC = fbase[0];
    half8  bfPC = fbase[64];
    float2 nwC  = nbase[0];
#pragma unroll
    for (int t = 0; t < 16; ++t) {
        half8 bfFN = bfFC, bfPN = bfPC;
        float2 nwN = nwC;
        if (t < 15) {                                // 1-deep prefetch
            bfFN = fbase[(t + 1) * 128];
            bfPN = fbase[(t + 1) * 128 + 64];
            nwN  = nbase[(t + 1) * 16];
        }
        // tile A
        {
            const f4 C1 = qfA - nwC.x;               // -(nf1'+nf2')
            const f4 C2 = qpA - nwC.y;               // -(np1'+np2')
            const f4 fd = __builtin_amdgcn_mfma_f32_16x16x32_f16(afFA, bfFC, C1, 0, 0, 0);
            const f4 pd = __builtin_amdgcn_mfma_f32_16x16x32_f16(afPA, bfPC, C2, 0, 0, 0);
            f4 ef;
#pragma unroll
            for (int e = 0; e < 4; ++e) ef[e] = __builtin_amdgcn_exp2f(fd[e]);
            sfA += ef;
            const float m = fmaxf(fmaxf(pd[0], pd[1]), fmaxf(pd[2], pd[3]));
            if (__any(m > PDCUT)) {                  // ~16% of tiles
                f4 ep;
#pragma unroll
                for (int e = 0; e < 4; ++e) ep[e] = __builtin_amdgcn_exp2f(pd[e]);
                spA += ep;
                tAA += ep * fd;
            }
        }
        // tile B
        {
            const f4 C1 = qfB - nwC.x;
            const f4 C2 = qpB - nwC.y;
            const f4 fd = __builtin_amdgcn_mfma_f32_16x16x32_f16(afFB, bfFC, C1, 0, 0, 0);
            const f4 pd = __builtin_amdgcn_mfma_f32_16x16x32_f16(afPB, bfPC, C2, 0, 0, 0);
            f4 ef;
#pragma unroll
            for (int e = 0; e < 4; ++e) ef[e] = __builtin_amdgcn_exp2f(fd[e]);
            sfB += ef;
            const float m = fmaxf(fmaxf(pd[0], pd[1]), fmaxf(pd[2], pd[3]));
            if (__any(m > PDCUT)) {
                f4 ep;
#pragma unroll
                for (int e = 0; e < 4; ++e) ep[e] = __builtin_amdgcn_exp2f(pd[e]);
                spB += ep;
                tAB += ep * fd;
            }
        }
        bfFC = bfFN; bfPC = bfPN; nwC = nwN;
    }

    // reduce over the 16 columns (lane bits 0..3), both tiles
#pragma unroll
    for (int m = 1; m < 16; m <<= 1) {
#pragma unroll
        for (int e = 0; e < 4; ++e) {
            spA[e] += __shfl_xor(spA[e], m);
            tAA[e] += __shfl_xor(tAA[e], m);
            sfA[e] += __shfl_xor(sfA[e], m);
            spB[e] += __shfl_xor(spB[e], m);
            tAB[e] += __shfl_xor(tAB[e], m);
            sfB[e] += __shfl_xor(sfB[e], m);
        }
    }
    if (lr == 0) {
#pragma unroll
        for (int e = 0; e < 4; ++e) {
            sS[wv][lk * 4 + e]      = spA[e];
            sT[wv][lk * 4 + e]      = tAA[e];
            sF[wv][lk * 4 + e]      = sfA[e];
            sS[wv][16 + lk * 4 + e] = spB[e];
            sT[wv][16 + lk * 4 + e] = tAB[e];
            sF[wv][16 + lk * 4 + e] = sfB[e];
        }
    }
    __syncthreads();

    if (tid < 32) {
        float sp_ = 0.f, tp_ = 0.f, sf_ = 0.f;
#pragma unroll
        for (int w = 0; w < 8; ++w) {
            sp_ += sS[w][tid];
            tp_ += sT[w][tid];
            sf_ += sF[w][tid];
        }
        float* P = part + (size_t)jh * 3 * ROWS_TOT;
        P[i0g + tid]                = sp_;
        P[ROWS_TOT + i0g + tid]     = tp_;
        P[2 * ROWS_TOT + i0g + tid] = sf_;
    }
}

// ---- k2: combine 2 j-half planes, ce + reg -> out ----
__global__ void k2_final(const float* __restrict__ part,
                         const float* __restrict__ regp,
                         const float* __restrict__ wg,
                         float* __restrict__ out) {
    __shared__ float redc[4], redr[4];
    const int tid = threadIdx.x;
    const int r = blockIdx.x * 256 + tid;
    const int b = r >> 12;

    const float* P0 = part;
    const float* P1 = part + (size_t)3 * ROWS_TOT;
    const float sp_ = P0[r] + P1[r];
    const float tp_ = P0[ROWS_TOT + r] + P1[ROWS_TOT + r];
    const float sf_ = P0[2*ROWS_TOT + r] + P1[2*ROWS_TOT + r];
    const float ce = __logf(sf_) - (tp_ * LN2) / sp_;
    float contrib = wg[r] * ce;
    float rr = regp[r];

#pragma unroll
    for (int off = 32; off > 0; off >>= 1) {
        contrib += __shfl_down(contrib, off);
        rr      += __shfl_down(rr, off);
    }
    const int wave = tid >> 6, lane = tid & 63;
    if (lane == 0) { redc[wave] = contrib; redr[wave] = rr; }
    __syncthreads();
    if (tid == 0) {
        atomicAdd(&out[b],     redc[0] + redc[1] + redc[2] + redc[3]);
        atomicAdd(&out[2 + b], (redr[0] + redr[1] + redr[2] + redr[3])
                               * (1.0f / (29.0f * (float)NPTS)));
    }
}

extern "C" void kernel_launch(void* const* d_in, const int* in_sizes, int n_in,
                              void* d_out, int out_size, void* d_ws, size_t ws_size,
                              hipStream_t stream) {
    const float* pts = (const float*)d_in[0];
    const float* f1  = (const float*)d_in[1];
    const float* f2  = (const float*)d_in[2];
    const float* wg  = (const float*)d_in[3];
    float* out = (float*)d_out;

    float* ws = (float*)d_ws;
    float2*    nrm1  = (float2*)ws;                  // 8192 float2
    float2*    nrm2  = (float2*)(ws + 16384);        // 8192 float2
    _Float16*  fragB = (_Float16*)(ws + 32768);      // 524288 halves
    _Float16*  fragA = (_Float16*)(ws + 294912);     // 524288 halves
    float*     regp  = ws + 557056;                  // 8192
    float*     part  = ws + 565248;                  // 2*3*8192

    kA_prep<<<ROWS_TOT / 64, 64, 0, stream>>>(pts, f1, f2, nrm1, nrm2,
                                              fragA, fragB, regp, out);
    kB_main<<<512, 512, 0, stream>>>(nrm1, nrm2, fragA, fragB, part);
    k2_final<<<ROWS_TOT / 256, 256, 0, stream>>>(part, regp, wg, out);
}

// Round 20
// 24.777 us; speedup vs baseline: 1.2183x; 1.2183x over previous
//
#include <hip/hip_runtime.h>
#include <math.h>

// DeepFeatureLoss: B=2, N=4096, D=32, fp32 in/out.
// out[0..1] = ce_loss[b], out[2..3] = reg_loss[b].
//
// ce_i = log(s_f) - t/s_p  (softmax max pinned at 0; dists <= 0):
//   s_p = sum_j exp(pd_ij), t = sum_j exp(pd_ij)*fd_ij, s_f = sum_j exp(fd_ij)
// exp2 units; t *= LN2 at finalize.
//
// R20 = R18 EXACT ROLLBACK (best: 25.0us, absmax 0.0). R19's ep-skip
// branch regressed to 30.2 (4th confirmation: any per-iter conditional in
// this unrolled loop costs ~5us in broken codegen). Final structure:
//  kA: combined f16 fragments per tile (128 half8: [0,64) feature *FSC,
//      [64,128) hi/lo-split point *PSC2, 12ch) + norm float2s + reg plane.
//  kB: MI=2 (one B-load feeds 2 i-tiles), 16 iters/wave, 1-deep prefetch;
//      per tile: 2 C-folded MFMAs emit fd'/pd' directly; 8 exp2; f4
//      accumulate. Issue-bound: both distance computations on matrix pipe,
//      epilogue = 2 exps + 3 VALU per output element (irreducible).
//  k2: combine j-half planes, ce + reg -> out.
//
// ws (floats): nrm1[0,16384) nrm2[16384,32768) fragB[32768,294912)
// fragA[294912,557056) regp[557056,565248) part[565248,614400).

#define NPTS 4096
#define ROWS_TOT 8192
#define DF 32

#define L2E  1.4426950408889634f
#define LN2  0.6931471805599453f
#define FSC  1.6986436f           // sqrt(2*log2e)
#define PSC2 339.72872f           // 200*sqrt(2*log2e)

typedef _Float16 half8 __attribute__((ext_vector_type(8)));
typedef float f4 __attribute__((ext_vector_type(4)));

// ---- kA: combined fragments (feature + hi/lo point) + norm float2s ----
__global__ void kA_prep(const float* __restrict__ pts,
                        const float* __restrict__ f1g,
                        const float* __restrict__ f2g,
                        float2* __restrict__ nrm1, float2* __restrict__ nrm2,
                        _Float16* __restrict__ fragA, _Float16* __restrict__ fragB,
                        float* __restrict__ regp, float* __restrict__ out) {
    const int r = blockIdx.x * 64 + threadIdx.x;     // 0..8191
    if (r < 4) out[r] = 0.0f;
    const int jt = r >> 4;                           // global tile id 0..511
    const int c  = r & 15;                           // row/col within tile

    float n1, n2, reg1, reg2;
    {   // features -> [0,64) of tile block
        const float4* f2v = (const float4*)(f2g + (size_t)r * DF);
        float vals[32]; float s = 0.0f;
#pragma unroll
        for (int q = 0; q < 8; ++q) {
            float4 v = f2v[q];
            vals[4*q]=v.x; vals[4*q+1]=v.y; vals[4*q+2]=v.z; vals[4*q+3]=v.w;
            s += v.x*v.x + v.y*v.y + v.z*v.z + v.w*v.w;
        }
        n2 = s;
        reg2 = s - vals[0]*vals[0] - vals[1]*vals[1] - vals[2]*vals[2];
        half8* fv = (half8*)fragB;
#pragma unroll
        for (int kb = 0; kb < 4; ++kb) {
            half8 h;
#pragma unroll
            for (int i = 0; i < 8; ++i) h[i] = (_Float16)(vals[kb*8+i] * FSC);
            fv[(size_t)jt*128 + kb*16 + c] = h;
        }
    }
    {
        const float4* f1v = (const float4*)(f1g + (size_t)r * DF);
        float vals[32]; float s = 0.0f;
#pragma unroll
        for (int q = 0; q < 8; ++q) {
            float4 v = f1v[q];
            vals[4*q]=v.x; vals[4*q+1]=v.y; vals[4*q+2]=v.z; vals[4*q+3]=v.w;
            s += v.x*v.x + v.y*v.y + v.z*v.z + v.w*v.w;
        }
        n1 = s;
        reg1 = s - vals[0]*vals[0] - vals[1]*vals[1] - vals[2]*vals[2];
        half8* fv = (half8*)fragA;
#pragma unroll
        for (int kb = 0; kb < 4; ++kb) {
            half8 h;
#pragma unroll
            for (int i = 0; i < 8; ++i) h[i] = (_Float16)(vals[kb*8+i] * FSC);
            fv[(size_t)jt*128 + kb*16 + c] = h;
        }
    }
    {   // points hi/lo -> [64,128) of tile block
        const float* pp = pts + (size_t)r * 3;
        const float v0 = pp[0]*PSC2, v1 = pp[1]*PSC2, v2 = pp[2]*PSC2;
        const float h0 = (float)(_Float16)v0, h1 = (float)(_Float16)v1,
                    h2 = (float)(_Float16)v2;
        const float l0 = v0 - h0, l1 = v1 - h1, l2 = v2 - h2;
        const float np = 0.5f * (v0*v0 + v1*v1 + v2*v2);

        // A ch0-11 = [h0,h1,h2,h0,h1,h2,l0,l1,l2,l0,l1,l2]
        // B ch0-11 = [h0,h1,h2,l0,l1,l2,h0,h1,h2,l0,l1,l2]
        const float pa[16] = {h0,h1,h2,h0,h1,h2,l0,l1,  l2,l0,l1,l2,0,0,0,0};
        const float pb[16] = {h0,h1,h2,l0,l1,l2,h0,h1,  h2,l0,l1,l2,0,0,0,0};
        half8* fa = (half8*)fragA;
        half8* fb = (half8*)fragB;
#pragma unroll
        for (int kb = 0; kb < 2; ++kb) {
            half8 ha, hb;
#pragma unroll
            for (int i = 0; i < 8; ++i) {
                ha[i] = (_Float16)pa[kb*8+i];
                hb[i] = (_Float16)pb[kb*8+i];
            }
            fa[(size_t)jt*128 + 64 + kb*16 + c] = ha;
            fb[(size_t)jt*128 + 64 + kb*16 + c] = hb;
        }
        const half8 z = {0,0,0,0,0,0,0,0};
        fa[(size_t)jt*128 + 64 + 32 + c] = z;  fa[(size_t)jt*128 + 64 + 48 + c] = z;
        fb[(size_t)jt*128 + 64 + 32 + c] = z;  fb[(size_t)jt*128 + 64 + 48 + c] = z;

        nrm1[r] = make_float2(-(n1 * L2E), -np);     // row side (negated)
        nrm2[r] = make_float2(  n2 * L2E,   np);     // col side (positive)
    }
    regp[r] = reg1 + reg2;
}

// ---- kB: MI=2; per iter: 2 frag loads + 1 float2 + 4 MFMA + 16 exp2 ----
__launch_bounds__(512)
__global__ void kB_main(const float2* __restrict__ nrm1,
                        const float2* __restrict__ nrm2,
                        const _Float16* __restrict__ fragA,
                        const _Float16* __restrict__ fragB,
                        float* __restrict__ part) {
    __shared__ float sS[8][32], sT[8][32], sF[8][32];

    const int tid = threadIdx.x;
    const int l = tid & 63, wv = tid >> 6;           // wave 0..7
    const int ip = blockIdx.x >> 1;                  // i-pair 0..255
    const int jh = blockIdx.x & 1;                   // j-half 0/1
    const int b  = ip >> 7;
    const int i0g = ip * 32;
    const int lr = l & 15, lk = l >> 4;

    // A fragments (feature + point) for both i-tiles
    const half8 afFA = ((const half8*)fragA)[(size_t)(ip*2)   * 128 + l];
    const half8 afPA = ((const half8*)fragA)[(size_t)(ip*2)   * 128 + 64 + l];
    const half8 afFB = ((const half8*)fragA)[(size_t)(ip*2+1) * 128 + l];
    const half8 afPB = ((const half8*)fragA)[(size_t)(ip*2+1) * 128 + 64 + l];

    const int rbA = i0g + lk * 4;
    const int rbB = i0g + 16 + lk * 4;
    f4 qfA, qpA, qfB, qpB;                           // -nf1', -np1' per row
#pragma unroll
    for (int e = 0; e < 4; ++e) {
        const float2 a = nrm1[rbA + e];
        const float2 bq = nrm1[rbB + e];
        qfA[e] = a.x;  qpA[e] = a.y;
        qfB[e] = bq.x; qpB[e] = bq.y;
    }

    const int jt0 = b * 256 + jh * 128 + wv * 16;
    const int j0  = b * NPTS + jh * 2048 + wv * 256 + lr;
    const half8*  fbase = (const half8*)fragB + ((size_t)jt0 * 128 + l);
    const float2* nbase = nrm2 + j0;

    f4 spA = {0,0,0,0}, tAA = {0,0,0,0}, sfA = {0,0,0,0};
    f4 spB = {0,0,0,0}, tAB = {0,0,0,0}, sfB = {0,0,0,0};

    half8  bfFC = fbase[0];
    half8  bfPC = fbase[64];
    float2 nwC  = nbase[0];
#pragma unroll
    for (int t = 0; t < 16; ++t) {
        half8 bfFN = bfFC, bfPN = bfPC;
        float2 nwN = nwC;
        if (t < 15) {                                // 1-deep prefetch
            bfFN = fbase[(t + 1) * 128];
            bfPN = fbase[(t + 1) * 128 + 64];
            nwN  = nbase[(t + 1) * 16];
        }
        // tile A
        {
            const f4 C1 = qfA - nwC.x;               // -(nf1'+nf2')
            const f4 C2 = qpA - nwC.y;               // -(np1'+np2')
            const f4 fd = __builtin_amdgcn_mfma_f32_16x16x32_f16(afFA, bfFC, C1, 0, 0, 0);
            const f4 pd = __builtin_amdgcn_mfma_f32_16x16x32_f16(afPA, bfPC, C2, 0, 0, 0);
            f4 ep, ef;
#pragma unroll
            for (int e = 0; e < 4; ++e) {
                ep[e] = __builtin_amdgcn_exp2f(pd[e]);
                ef[e] = __builtin_amdgcn_exp2f(fd[e]);
            }
            spA += ep; tAA += ep * fd; sfA += ef;
        }
        // tile B
        {
            const f4 C1 = qfB - nwC.x;
            const f4 C2 = qpB - nwC.y;
            const f4 fd = __builtin_amdgcn_mfma_f32_16x16x32_f16(afFB, bfFC, C1, 0, 0, 0);
            const f4 pd = __builtin_amdgcn_mfma_f32_16x16x32_f16(afPB, bfPC, C2, 0, 0, 0);
            f4 ep, ef;
#pragma unroll
            for (int e = 0; e < 4; ++e) {
                ep[e] = __builtin_amdgcn_exp2f(pd[e]);
                ef[e] = __builtin_amdgcn_exp2f(fd[e]);
            }
            spB += ep; tAB += ep * fd; sfB += ef;
        }
        bfFC = bfFN; bfPC = bfPN; nwC = nwN;
    }

    // reduce over the 16 columns (lane bits 0..3), both tiles
#pragma unroll
    for (int m = 1; m < 16; m <<= 1) {
#pragma unroll
        for (int e = 0; e < 4; ++e) {
            spA[e] += __shfl_xor(spA[e], m);
            tAA[e] += __shfl_xor(tAA[e], m);
            sfA[e] += __shfl_xor(sfA[e], m);
            spB[e] += __shfl_xor(spB[e], m);
            tAB[e] += __shfl_xor(tAB[e], m);
            sfB[e] += __shfl_xor(sfB[e], m);
        }
    }
    if (lr == 0) {
#pragma unroll
        for (int e = 0; e < 4; ++e) {
            sS[wv][lk * 4 + e]      = spA[e];
            sT[wv][lk * 4 + e]      = tAA[e];
            sF[wv][lk * 4 + e]      = sfA[e];
            sS[wv][16 + lk * 4 + e] = spB[e];
            sT[wv][16 + lk * 4 + e] = tAB[e];
            sF[wv][16 + lk * 4 + e] = sfB[e];
        }
    }
    __syncthreads();

    if (tid < 32) {
        float sp_ = 0.f, tp_ = 0.f, sf_ = 0.f;
#pragma unroll
        for (int w = 0; w < 8; ++w) {
            sp_ += sS[w][tid];
            tp_ += sT[w][tid];
            sf_ += sF[w][tid];
        }
        float* P = part + (size_t)jh * 3 * ROWS_TOT;
        P[i0g + tid]                = sp_;
        P[ROWS_TOT + i0g + tid]     = tp_;
        P[2 * ROWS_TOT + i0g + tid] = sf_;
    }
}

// ---- k2: combine 2 j-half planes, ce + reg -> out ----
__global__ void k2_final(const float* __restrict__ part,
                         const float* __restrict__ regp,
                         const float* __restrict__ wg,
                         float* __restrict__ out) {
    __shared__ float redc[4], redr[4];
    const int tid = threadIdx.x;
    const int r = blockIdx.x * 256 + tid;
    const int b = r >> 12;

    const float* P0 = part;
    const float* P1 = part + (size_t)3 * ROWS_TOT;
    const float sp_ = P0[r] + P1[r];
    const float tp_ = P0[ROWS_TOT + r] + P1[ROWS_TOT + r];
    const float sf_ = P0[2*ROWS_TOT + r] + P1[2*ROWS_TOT + r];
    const float ce = __logf(sf_) - (tp_ * LN2) / sp_;
    float contrib = wg[r] * ce;
    float rr = regp[r];

#pragma unroll
    for (int off = 32; off > 0; off >>= 1) {
        contrib += __shfl_down(contrib, off);
        rr      += __shfl_down(rr, off);
    }
    const int wave = tid >> 6, lane = tid & 63;
    if (lane == 0) { redc[wave] = contrib; redr[wave] = rr; }
    __syncthreads();
    if (tid == 0) {
        atomicAdd(&out[b],     redc[0] + redc[1] + redc[2] + redc[3]);
        atomicAdd(&out[2 + b], (redr[0] + redr[1] + redr[2] + redr[3])
                               * (1.0f / (29.0f * (float)NPTS)));
    }
}

extern "C" void kernel_launch(void* const* d_in, const int* in_sizes, int n_in,
                              void* d_out, int out_size, void* d_ws, size_t ws_size,
                              hipStream_t stream) {
    const float* pts = (const float*)d_in[0];
    const float* f1  = (const float*)d_in[1];
    const float* f2  = (const float*)d_in[2];
    const float* wg  = (const float*)d_in[3];
    float* out = (float*)d_out;

    float* ws = (float*)d_ws;
    float2*    nrm1  = (float2*)ws;                  // 8192 float2
    float2*    nrm2  = (float2*)(ws + 16384);        // 8192 float2
    _Float16*  fragB = (_Float16*)(ws + 32768);      // 524288 halves
    _Float16*  fragA = (_Float16*)(ws + 294912);     // 524288 halves
    float*     regp  = ws + 557056;                  // 8192
    float*     part  = ws + 565248;                  // 2*3*8192

    kA_prep<<<ROWS_TOT / 64, 64, 0, stream>>>(pts, f1, f2, nrm1, nrm2,
                                              fragA, fragB, regp, out);
    kB_main<<<512, 512, 0, stream>>>(nrm1, nrm2, fragA, fragB, part);
    k2_final<<<ROWS_TOT / 256, 256, 0, stream>>>(part, regp, wg, out);
}